// Round 1
// 4028.130 us; speedup vs baseline: 3.5382x; 3.5382x over previous
//
#include <hip/hip_runtime.h>
#include <hip/hip_bf16.h>

// RK4 latent ODE: f(y) = tanh(y@W1+b1)@W2 + b2. B=1024, D=512, H=1024, T=64.
// R6 passed (absmax 0.031) at 14.25 ms: per-CU vmem service rate on strided
// weight loads (16x64B segments/instr, ~65 cyc/instr, L1 thrash) is the
// bottleneck -- MfmaUtil 1.5%, HBM 0.13%, LDS conflicts 2%.
// R7: pre-pack weights into per-wave FRAGMENT-STREAM order so every inner-loop
// wave load is one contiguous 1KB segment (lane-linear), sequential across
// K-iterations. Compute structure, numerics, and mapping identical to R6
// (fp32 out, in_sizes role mapping, runtime dtype detect, fp16 weights/acts,
// fp32 state).

#define B_ 1024
#define D_ 512
#define H_ 1024
#define T_ 64
#define M_ 16   // batch rows per block
#define NW 16   // waves per block

typedef unsigned short ushort_t;
typedef _Float16 f16x8 __attribute__((ext_vector_type(8)));
typedef float f32x4 __attribute__((ext_vector_type(4)));
typedef unsigned short ushortx8 __attribute__((ext_vector_type(8)));

__device__ __forceinline__ float bf2f(ushort_t u) {
  union { unsigned u; float f; } v;
  v.u = ((unsigned)u) << 16;
  return v.f;
}

__device__ __forceinline__ ushort_t f2h(float f) {
  return __builtin_bit_cast(ushort_t, (_Float16)f);   // RNE fp16
}

// dual-dtype scalar read: fp32 or bf16 element i
__device__ __forceinline__ float ldf(const void* p, int i, bool f32) {
  return f32 ? ((const float*)p)[i] : bf2f(((const ushort_t*)p)[i]);
}

__device__ __forceinline__ bool is_f32_inputs(const void* ts) {
  // fp32: ts[0]=0.0f -> ushort[1] (high half) == 0; bf16: ts[1]=bf16(1/63)!=0
  return ((const ushort_t*)ts)[1] == 0;
}

__device__ __forceinline__ float tanh_fast(float x) {
  float e = __builtin_amdgcn_exp2f(x * 2.885390081777927f);  // exp(2x)
  return 1.0f - 2.0f * __builtin_amdgcn_rcpf(e + 1.0f);      // NaN-free
}

__device__ __forceinline__ f16x8 ld8(const ushort_t* p) {
  return __builtin_bit_cast(f16x8, *(const ushortx8*)p);
}

__device__ __forceinline__ f32x4 mfma16f(f16x8 a, f16x8 b, f32x4 c) {
  return __builtin_amdgcn_mfma_f32_16x16x32_f16(a, b, c, 0, 0, 0);
}

// ---- prep: pack W1 [D][H] (fp32/bf16) into per-wave fragment stream (fp16) ----
// w1f half index: (((w*16 + t)*4 + n)*64 + l)*8 + j
//   = fp16( W1[ t*32 + (l>>4)*8 + j ][ w*64 + n*16 + (l&15) ] )
// so wave w, K-iter t, MFMA-col-tile n reads ONE contiguous 1KB (lane-linear).
__global__ void pack_w1(const void* __restrict__ in, ushort_t* __restrict__ out,
                        const void* __restrict__ ts) {
  const bool f32 = is_f32_inputs(ts);
  const int tid = blockIdx.x * blockDim.x + threadIdx.x;  // 0..65535
  const int l = tid & 63;
  const int n = (tid >> 6) & 3;
  const int t = (tid >> 8) & 15;
  const int w = tid >> 12;          // 0..15
  const int m = l & 15, q = l >> 4;
  const int c  = w * 64 + n * 16 + m;   // H index
  const int kb = t * 32 + q * 8;        // D (K) index base
  ushortx8 v;
#pragma unroll
  for (int j = 0; j < 8; j++)
    v[j] = f2h(ldf(in, (size_t)(kb + j) * H_ + c, f32));
  *(ushortx8*)(out + (size_t)tid * 8) = v;
}

// ---- prep: pack W2 [H][D] (fp32/bf16) into per-wave fragment stream (fp16) ----
// w2f half index: (((w*16 + t)*4 + u)*64 + l)*8 + j,  u = n*2 + h
//   = fp16( W2[ t*64 + h*32 + (l>>4)*8 + j ][ w*32 + n*16 + (l&15) ] )
__global__ void pack_w2(const void* __restrict__ in, ushort_t* __restrict__ out,
                        const void* __restrict__ ts) {
  const bool f32 = is_f32_inputs(ts);
  const int tid = blockIdx.x * blockDim.x + threadIdx.x;  // 0..65535
  const int l = tid & 63;
  const int u = (tid >> 6) & 3;
  const int t = (tid >> 8) & 15;
  const int w = tid >> 12;          // 0..15
  const int n = u >> 1, h = u & 1;
  const int m = l & 15, q = l >> 4;
  const int c  = w * 32 + n * 16 + m;       // D index
  const int kb = t * 64 + h * 32 + q * 8;   // H (K) index base
  ushortx8 v;
#pragma unroll
  for (int j = 0; j < 8; j++)
    v[j] = f2h(ldf(in, (size_t)(kb + j) * D_ + c, f32));
  *(ushortx8*)(out + (size_t)tid * 8) = v;
}

// ---- main trajectory kernel: 64 blocks x 1024 threads (16 waves) ----
// Per wave w (0..15), lane l: m=l&15, quad=l>>4.
// A map: A[m][quad*8+j]; B map: B[quad*8+j][col]; C/D: row=quad*4+r, col=m.
// GEMM1: wave owns h cols [w*64, w*64+64):   4 tiles, K=512  (16 iters)
// GEMM2: wave owns k cols [w*32, w*32+32):   2 tiles, K=1024 (16 iters)
// Weight loads: contiguous 1KB per instr from packed streams (R7).
__global__ __launch_bounds__(1024, 4)
void rk4_kernel(const void* __restrict__ y0,     // [B][D]
                const void* __restrict__ ts,     // [T]
                const ushort_t* __restrict__ w1f,// packed W1 fragment stream
                const void* __restrict__ b1,     // [H]
                const ushort_t* __restrict__ w2f,// packed W2 fragment stream
                const void* __restrict__ b2,     // [D]
                float* __restrict__ out)         // [T][B][D] fp32
{
  __shared__ __align__(16) ushort_t yS[M_][D_ + 8];   // fp16 yin
  __shared__ __align__(16) ushort_t hS[M_][H_ + 8];   // fp16 h

  const bool f32i = is_f32_inputs(ts);
  const int tid  = threadIdx.x;
  const int wave = tid >> 6;
  const int lane = tid & 63;
  const int m    = lane & 15;
  const int quad = lane >> 4;
  const int rowbase = blockIdx.x * M_;
  const int cw1 = wave * 64;    // GEMM1 output col base (H index)
  const int cw2 = wave * 32;    // GEMM2 output col base (D index)

  float b1v[4], b2v[2];
#pragma unroll
  for (int n = 0; n < 4; n++) b1v[n] = ldf(b1, cw1 + n * 16 + m, f32i);
#pragma unroll
  for (int n = 0; n < 2; n++) b2v[n] = ldf(b2, cw2 + n * 16 + m, f32i);

  // per-wave packed weight stream bases (contiguous 64KB per wave)
  const ushort_t* q1 = w1f + ((size_t)wave << 15) + lane * 8;
  const ushort_t* q2 = w2f + ((size_t)wave << 15) + lane * 8;

  // state: element (n,r) <-> global row rowbase+quad*4+r, col cw2+n*16+m
  float y[2][4], acc[2][4], k[2][4];
#pragma unroll
  for (int n = 0; n < 2; n++)
#pragma unroll
    for (int r = 0; r < 4; r++) {
      const int row = rowbase + quad * 4 + r;
      const int col = cw2 + n * 16 + m;
      y[n][r] = ldf(y0, row * D_ + col, f32i);
      out[(size_t)row * D_ + col] = y[n][r];   // t=0 plane
      k[n][r] = 0.0f;
      acc[n][r] = 0.0f;
    }

#pragma unroll 1
  for (int step = 0; step < T_ - 1; step++) {
    const float dt = ldf(ts, step + 1, f32i) - ldf(ts, step, f32i);

#pragma unroll 1
    for (int e = 0; e < 4; e++) {
      const float c = (e == 0) ? 0.0f : ((e == 3) ? dt : 0.5f * dt);
      const float w = ((e == 1) || (e == 2)) ? 2.0f : 1.0f;

      // ---- stage yin = y + c*k into LDS (fp16) ----
#pragma unroll
      for (int n = 0; n < 2; n++)
#pragma unroll
        for (int r = 0; r < 4; r++)
          yS[quad * 4 + r][cw2 + n * 16 + m] = f2h(y[n][r] + c * k[n][r]);
      __syncthreads();

      // ---- GEMM1: h = yin @ W1 (4 tiles, 16 K-iters, depth-1 prefetch) ----
      f32x4 hacc[4];
#pragma unroll
      for (int n = 0; n < 4; n++) hacc[n] = (f32x4){0.f, 0.f, 0.f, 0.f};
      f16x8 a0 = ld8(&yS[m][quad * 8]);
      f16x8 bb[4];
#pragma unroll
      for (int n = 0; n < 4; n++) bb[n] = ld8(q1 + n * 512);
#pragma unroll 1
      for (int t = 0; t < 16; t++) {
        const int tn = (t + 1 < 16) ? (t + 1) : 0;   // dummy wrap prefetch
        f16x8 a1 = ld8(&yS[m][tn * 32 + quad * 8]);
        f16x8 bn[4];
#pragma unroll
        for (int n = 0; n < 4; n++) bn[n] = ld8(q1 + tn * 2048 + n * 512);
#pragma unroll
        for (int n = 0; n < 4; n++) hacc[n] = mfma16f(a0, bb[n], hacc[n]);
        a0 = a1;
#pragma unroll
        for (int n = 0; n < 4; n++) bb[n] = bn[n];
      }

      // ---- bias + tanh -> hS (fp16) ----
#pragma unroll
      for (int n = 0; n < 4; n++)
#pragma unroll
        for (int r = 0; r < 4; r++)
          hS[quad * 4 + r][cw1 + n * 16 + m] = f2h(tanh_fast(hacc[n][r] + b1v[n]));
      __syncthreads();

      // ---- GEMM2: k = h @ W2 + b2 (2 tiles, K=1024, x2-unrolled, prefetch) ----
      f32x4 kacc[2];
#pragma unroll
      for (int n = 0; n < 2; n++) kacc[n] = (f32x4){0.f, 0.f, 0.f, 0.f};
      f16x8 c0 = ld8(&hS[m][quad * 8]);
      f16x8 c1 = ld8(&hS[m][32 + quad * 8]);
      f16x8 db[4];   // [n*2+h]: h = K-half within 64-chunk
#pragma unroll
      for (int u = 0; u < 4; u++) db[u] = ld8(q2 + u * 512);
#pragma unroll 1
      for (int t = 0; t < 16; t++) {
        const int tn = (t + 1 < 16) ? (t + 1) : 0;   // dummy wrap prefetch
        f16x8 a1 = ld8(&hS[m][tn * 64 + quad * 8]);
        f16x8 a2 = ld8(&hS[m][tn * 64 + 32 + quad * 8]);
        f16x8 dn[4];
#pragma unroll
        for (int u = 0; u < 4; u++) dn[u] = ld8(q2 + tn * 2048 + u * 512);
#pragma unroll
        for (int n = 0; n < 2; n++) {
          kacc[n] = mfma16f(c0, db[n * 2], kacc[n]);
          kacc[n] = mfma16f(c1, db[n * 2 + 1], kacc[n]);
        }
        c0 = a1; c1 = a2;
#pragma unroll
        for (int u = 0; u < 4; u++) db[u] = dn[u];
      }

#pragma unroll
      for (int n = 0; n < 2; n++)
#pragma unroll
        for (int r = 0; r < 4; r++) {
          k[n][r] = kacc[n][r] + b2v[n];
          if (e == 0) acc[n][r] = k[n][r];
          else        acc[n][r] += w * k[n][r];
        }
    }

    // ---- y update + fp32 output store ----
    float* op = out + (size_t)(step + 1) * B_ * D_;
    const float s = dt * (1.0f / 6.0f);
#pragma unroll
    for (int n = 0; n < 2; n++)
#pragma unroll
      for (int r = 0; r < 4; r++) {
        y[n][r] += s * acc[n][r];
        op[(size_t)(rowbase + quad * 4 + r) * D_ + cw2 + n * 16 + m] = y[n][r];
      }
  }
}

extern "C" void kernel_launch(void* const* d_in, const int* in_sizes, int n_in,
                              void* d_out, int out_size, void* d_ws, size_t ws_size,
                              hipStream_t stream) {
  // ---- role mapping from in_sizes (proven R5): elements-or-bytes, dict-or-alpha ----
  int iTs = -1, sc = 1;
  for (int i = 0; i < n_in; i++)
    if (in_sizes[i] == 64 || in_sizes[i] == 128 || in_sizes[i] == 256) {
      iTs = i; sc = in_sizes[i] / 64; break;
    }
  if (iTs < 0) { iTs = 1; sc = 1; }
  int iB1 = -1, iB2 = -1, bigs[3]; int nb = 0;
  for (int i = 0; i < n_in; i++) {
    if (i == iTs) continue;
    if (in_sizes[i] == 1024 * sc) iB1 = i;
    else if (in_sizes[i] == 512 * sc) iB2 = i;
    else if (nb < 3) bigs[nb++] = i;
  }
  if (iB1 < 0) iB1 = 3;
  if (iB2 < 0) iB2 = 5;
  if (nb < 3) { bigs[0] = 0; bigs[1] = 2; bigs[2] = 4; }
  const void *y0, *w1, *w2;
  if (iTs == 1) {            // dict order: first_point, ts, W1, b1, W2, b2
    y0 = d_in[bigs[0]]; w1 = d_in[bigs[1]]; w2 = d_in[bigs[2]];
  } else {                   // alphabetical: W1, W2, b1, b2, first_point, ts
    w1 = d_in[bigs[0]]; w2 = d_in[bigs[1]]; y0 = d_in[bigs[2]];
  }
  const void* ts = d_in[iTs];
  const void* b1 = d_in[iB1];
  const void* b2 = d_in[iB2];
  float* out = (float*)d_out;

  // ws: w1f fp16 stream (1 MB) | w2f fp16 stream (1 MB)
  ushort_t* w1f = (ushort_t*)d_ws;
  ushort_t* w2f = w1f + (size_t)D_ * H_;

  pack_w1<<<dim3(256), dim3(256), 0, stream>>>(w1, w1f, ts);
  pack_w2<<<dim3(256), dim3(256), 0, stream>>>(w2, w2f, ts);

  rk4_kernel<<<dim3(B_ / M_), dim3(1024), 0, stream>>>(y0, ts, w1f, b1, w2f, b2, out);
}